// Round 4
// baseline (300.667 us; speedup 1.0000x reference)
//
#include <hip/hip_runtime.h>

// LSTM cell, fully fused: B=1024, U=2048
//   d_out = [h_new, h_new, c_new] computed directly in the GEMM epilogue.
// Block = 128 rows x 32 u-cols, computing all 4 gate tiles (n' = gate*32+du,
// effective 128x128 MFMA tile). 4 waves, each 32 rows x 128 n'-cols.
// GEMM core identical to R2: reg-staged fp32->bf16 (cvt_pk), LDS dbuf,
// XOR swizzle, 2-deep prefetch pipeline.

#define BDIM   1024
#define UDIM   2048
#define KDIM   4096
#define NDIM   8192
#define BM 128
#define BK 64
#define NT (KDIM / BK)

typedef __attribute__((ext_vector_type(4))) float        f32x4;
typedef __attribute__((ext_vector_type(8))) short        short8;
typedef __attribute__((ext_vector_type(4))) unsigned int u32x4;

__device__ inline unsigned int cvt_pk_bf16(float lo, float hi) {
    unsigned int r;
    asm("v_cvt_pk_bf16_f32 %0, %1, %2" : "=v"(r) : "v"(lo), "v"(hi));
    return r;
}
__device__ inline float fast_sigmoid(float v) {
    return __builtin_amdgcn_rcpf(1.f + __expf(-v));
}
__device__ inline float fast_tanh(float v) {
    float t = __expf(-2.f * __builtin_fabsf(v));
    float r = (1.f - t) * __builtin_amdgcn_rcpf(1.f + t);
    return __builtin_copysignf(r, v);
}

__global__ __launch_bounds__(256, 2)
void lstm_fused(const float* __restrict__ x, const float* __restrict__ h,
                const float* __restrict__ c, const float* __restrict__ w,
                float* __restrict__ out) {
    __shared__ unsigned short As[2][BM * BK];   // 2 x 16 KiB
    __shared__ unsigned short Bs[2][BM * BK];   // 2 x 16 KiB (128 n' x 64 k)

    const int tid  = threadIdx.x;
    const int lane = tid & 63;
    const int wid  = tid >> 6;       // wave 0..3 -> rows [wid*32, wid*32+32)
    const int lrow = lane & 15;
    const int lk   = lane >> 4;

    const int m0 = blockIdx.y * BM;
    const int u0 = blockIdx.x * 32;  // u-strip

    f32x4 acc[2][8];
#pragma unroll
    for (int i = 0; i < 2; ++i)
#pragma unroll
        for (int j = 0; j < 8; ++j)
            acc[i][j] = (f32x4){0.f, 0.f, 0.f, 0.f};

    f32x4 av[4][2];
    float bv[4][8];

    auto loadA = [&](int t) {
        int k0 = t * BK;
        const float* src = (k0 < UDIM) ? x + (size_t)m0 * UDIM + k0
                                       : h + (size_t)m0 * UDIM + (k0 - UDIM);
#pragma unroll
        for (int p = 0; p < 4; ++p) {
            int e = p * 256 + tid, arow = e >> 3, k8 = (e & 7) * 8;
            const float* gp = src + (size_t)arow * UDIM + k8;
            av[p][0] = *(const f32x4*)gp;
            av[p][1] = *(const f32x4*)(gp + 4);
        }
    };
    auto loadB = [&](int t) {
        int k0 = t * BK;
#pragma unroll
        for (int p = 0; p < 4; ++p) {
            int q = p * 256 + tid, np = q & 127, kg = q >> 7;
            int col = (np >> 5) * UDIM + u0 + (np & 31);   // gate*2048 + u
            const float* gp = w + (size_t)(k0 + kg * 8) * NDIM + col;
#pragma unroll
            for (int j = 0; j < 8; ++j) bv[p][j] = gp[(size_t)j * NDIM];
        }
    };
    auto writeAB = [&](int buf) {
        char* AsB = (char*)As[buf];
        char* BsB = (char*)Bs[buf];
#pragma unroll
        for (int p = 0; p < 4; ++p) {
            int e = p * 256 + tid, arow = e >> 3, k8 = (e & 7) * 8;
            u32x4 u;
            u[0] = cvt_pk_bf16(av[p][0][0], av[p][0][1]);
            u[1] = cvt_pk_bf16(av[p][0][2], av[p][0][3]);
            u[2] = cvt_pk_bf16(av[p][1][0], av[p][1][1]);
            u[3] = cvt_pk_bf16(av[p][1][2], av[p][1][3]);
            *(u32x4*)(AsB + arow * 128 + ((k8 * 2) ^ ((arow & 7) << 4))) = u;
        }
#pragma unroll
        for (int p = 0; p < 4; ++p) {
            int q = p * 256 + tid, np = q & 127, kg = q >> 7;
            u32x4 u;
#pragma unroll
            for (int j = 0; j < 4; ++j)
                u[j] = cvt_pk_bf16(bv[p][2 * j], bv[p][2 * j + 1]);
            *(u32x4*)(BsB + np * 128 + ((kg * 16) ^ ((np & 7) << 4))) = u;
        }
    };
    auto compute = [&](int buf) {
        const char* AsB = (const char*)As[buf];
        const char* BsB = (const char*)Bs[buf];
#pragma unroll
        for (int kk = 0; kk < 2; ++kk) {
            short8 af[2], bfr[8];
            int kb = kk * 64 + lk * 16;
#pragma unroll
            for (int mi = 0; mi < 2; ++mi) {
                int row = wid * 32 + mi * 16 + lrow;
                af[mi] = *(const short8*)(AsB + row * 128 + (kb ^ ((row & 7) << 4)));
            }
#pragma unroll
            for (int ni = 0; ni < 8; ++ni) {
                int row = ni * 16 + lrow;
                bfr[ni] = *(const short8*)(BsB + row * 128 + (kb ^ ((row & 7) << 4)));
            }
#pragma unroll
            for (int mi = 0; mi < 2; ++mi)
#pragma unroll
                for (int ni = 0; ni < 8; ++ni)
                    acc[mi][ni] = __builtin_amdgcn_mfma_f32_16x16x32_bf16(
                        af[mi], bfr[ni], acc[mi][ni], 0, 0, 0);
        }
    };

    loadA(0); loadB(0);
    writeAB(0);
    loadA(1); loadB(1);
    __syncthreads();

    for (int t = 0; t < NT; ++t) {
        int cur = t & 1;
        if (t + 1 < NT) {
            writeAB(cur ^ 1);
            if (t + 2 < NT) { loadA(t + 2); loadB(t + 2); }
        }
        compute(cur);
        __syncthreads();
    }

    // ---- fused gate epilogue ----
    // acc[mi][ni], C-row = m0+wid*32+mi*16+lk*4+r, n' = ni*16+lrow,
    // gate = ni>>1, du = (ni&1)*16+lrow.
    const size_t M = (size_t)BDIM * UDIM;
#pragma unroll
    for (int mi = 0; mi < 2; ++mi) {
        int rbase = m0 + wid * 32 + mi * 16 + lk * 4;
#pragma unroll
        for (int half = 0; half < 2; ++half) {
            int u = u0 + half * 16 + lrow;
            f32x4 iv = acc[mi][0 + half];
            f32x4 fv = acc[mi][2 + half];
            f32x4 gv = acc[mi][4 + half];
            f32x4 ov = acc[mi][6 + half];
#pragma unroll
            for (int r = 0; r < 4; ++r) {
                size_t off = (size_t)(rbase + r) * UDIM + u;
                float cc = fast_sigmoid(fv[r]) * c[off] +
                           fast_sigmoid(iv[r]) * fast_tanh(gv[r]);
                float hh = fast_sigmoid(ov[r]) * fast_tanh(cc);
                out[off]         = hh;
                out[M + off]     = hh;
                out[2 * M + off] = cc;
            }
        }
    }
}

extern "C" void kernel_launch(void* const* d_in, const int* in_sizes, int n_in,
                              void* d_out, int out_size, void* d_ws, size_t ws_size,
                              hipStream_t stream) {
    const float* x = (const float*)d_in[0];
    const float* h = (const float*)d_in[1];
    const float* c = (const float*)d_in[2];
    const float* w = (const float*)d_in[3];
    float* out = (float*)d_out;

    dim3 grid(UDIM / 32, BDIM / BM);        // (64, 8) = 512 blocks
    lstm_fused<<<grid, 256, 0, stream>>>(x, h, c, w, out);
}